// Round 7
// baseline (260.458 us; speedup 1.0000x reference)
//
#include <hip/hip_runtime.h>
#include <math.h>

typedef __attribute__((ext_vector_type(8))) short short8;
typedef __attribute__((ext_vector_type(4))) float f32x4;
typedef __attribute__((ext_vector_type(16))) float f32x16;
typedef __attribute__((ext_vector_type(4))) int int32x4;
typedef unsigned short bf16_t;

#define GLOAD_LDS16(g, l)                                                   \
    __builtin_amdgcn_global_load_lds(                                       \
        (__attribute__((address_space(1))) void*)(g),                       \
        (__attribute__((address_space(3))) void*)(l), 16, 0, 0)

__device__ __forceinline__ bf16_t f2b_rne(float f) {
    unsigned int u = __float_as_uint(f);
    u += 0x7FFFu + ((u >> 16) & 1u);
    return (bf16_t)(u >> 16);
}

// ---------------------------------------------------------------------------
// fp32 -> bf16 conversion
// ---------------------------------------------------------------------------
__global__ __launch_bounds__(256) void f2b_kernel(const float* __restrict__ in,
                                                  bf16_t* __restrict__ out, int n4) {
    int stride = gridDim.x * 256;
    for (int i = blockIdx.x * 256 + threadIdx.x; i < n4; i += stride) {
        float4 v = ((const float4*)in)[i];
        ushort4 p;
        p.x = f2b_rne(v.x); p.y = f2b_rne(v.y);
        p.z = f2b_rne(v.z); p.w = f2b_rne(v.w);
        ((ushort4*)out)[i] = p;
    }
}

// ---------------------------------------------------------------------------
// Relative-position bias table: tab[h][(k-q)+1023]  (validated round 2)
// ---------------------------------------------------------------------------
__global__ void build_bias_tab(const float* __restrict__ emb, float* __restrict__ tab) {
    int idx = blockIdx.x * 256 + threadIdx.x;
    if (idx >= 2047) return;
    int rel = idx - 1023;
    int rb = rel > 0 ? 16 : 0;
    int rp = rel < 0 ? -rel : rel;
    int bucket;
    if (rp < 8) {
        bucket = rb + rp;
    } else {
        float t = logf((float)rp * 0.125f);
        int vi = 8 + (int)(t / 2.772588722239781f * 8.0f);
        bucket = rb + (vi < 15 ? vi : 15);
    }
    #pragma unroll
    for (int hh = 0; hh < 16; hh++)
        tab[hh * 2048 + idx] = emb[bucket * 16 + hh];
}

// ---------------------------------------------------------------------------
// bf16 MFMA GEMM, 128x128 tile, BK=32, XCD swizzle, conflict-free LDS:
// stage-side pre-swizzle of global source col (slot ^= (row>>1)&3), read-side
// same XOR -> per-8-lane-phase banks all distinct (was 8-way conflict).
// MODE 0: row-major OT output.  MODE 1: write QKV into MFMA fragment layouts
//   qlin/klin[bh][t][s][lane][j] = X[seq = t*32+(lane&31)][d = 16s+8(lane>>5)+j]
//   vlin[bh][t][i][lane][j]      = V[seq = t*32+16(i&1)+8(lane>>5)+j][d=(lane&31)+32(i>>1)]
// ---------------------------------------------------------------------------
template <int MODE, typename OT>
__global__ __launch_bounds__(256) void gemm_mfma(const bf16_t* __restrict__ A,
                                                 const bf16_t* __restrict__ B,
                                                 OT* __restrict__ C, int N, int gx,
                                                 bf16_t* __restrict__ qlin,
                                                 bf16_t* __restrict__ klin,
                                                 bf16_t* __restrict__ vlin) {
    __shared__ __align__(16) bf16_t As[128 * 32];
    __shared__ __align__(16) bf16_t Bs[128 * 32];
    const int nwg = gridDim.x;
    const int cpx = nwg >> 3;
    const int swz = (blockIdx.x & 7) * cpx + (blockIdx.x >> 3);
    const int bx = swz % gx, by = swz / gx;

    const int tid = threadIdx.x;
    const int lane = tid & 63;
    const int wv = tid >> 6;
    const int wr = wv >> 1, wc = wv & 1;
    const int m0 = by * 128, n0 = bx * 128;
    const int cc = lane & 15, cg = lane >> 4;

    f32x4 acc[4][4];
    #pragma unroll
    for (int i = 0; i < 4; i++)
        #pragma unroll
        for (int j = 0; j < 4; j++) acc[i][j] = {0.f, 0.f, 0.f, 0.f};

    const int rsw = (cc >> 1) & 3;  // read-side XOR term, same for A and B rows

    for (int k0 = 0; k0 < 1024; k0 += 32) {
        __syncthreads();
        #pragma unroll
        for (int it = 0; it < 2; it++) {
            int c = it * 256 + tid;
            int r = c >> 2, sl = c & 3;
            int kc = (sl ^ ((r >> 1) & 3)) * 8;    // pre-swizzled source col
            GLOAD_LDS16(A + (size_t)(m0 + r) * 1024 + k0 + kc, &As[c * 8]);
            GLOAD_LDS16(B + (size_t)(n0 + r) * 1024 + k0 + kc, &Bs[c * 8]);
        }
        __syncthreads();

        short8 af[4], bf[4];
        #pragma unroll
        for (int mf = 0; mf < 4; mf++)
            af[mf] = *(const short8*)&As[(wr * 64 + mf * 16 + cc) * 32 + (cg ^ rsw) * 8];
        #pragma unroll
        for (int nf = 0; nf < 4; nf++)
            bf[nf] = *(const short8*)&Bs[(wc * 64 + nf * 16 + cc) * 32 + (cg ^ rsw) * 8];
        #pragma unroll
        for (int mf = 0; mf < 4; mf++)
            #pragma unroll
            for (int nf = 0; nf < 4; nf++)
                acc[mf][nf] = __builtin_amdgcn_mfma_f32_16x16x32_bf16(
                    af[mf], bf[nf], acc[mf][nf], 0, 0, 0);
    }

    if constexpr (MODE == 0) {
        #pragma unroll
        for (int mf = 0; mf < 4; mf++)
            #pragma unroll
            for (int j = 0; j < 4; j++) {
                size_t row = (size_t)(m0 + wr * 64 + mf * 16 + cg * 4 + j);
                OT* cp = C + row * N + n0 + wc * 64 + cc;
                #pragma unroll
                for (int nf = 0; nf < 4; nf++) cp[nf * 16] = acc[mf][nf][j];
            }
    } else {
        // fragment-order scatter; part & h are wave-uniform
        const int part = n0 >> 10;                      // 0=q 1=k 2=v
        const int h = ((n0 + wc * 64) >> 6) & 15;
        #pragma unroll
        for (int mf = 0; mf < 4; mf++)
            #pragma unroll
            for (int j = 0; j < 4; j++) {
                int row = m0 + wr * 64 + mf * 16 + cg * 4 + j;
                int bi = row >> 10, seq = row & 1023;
                size_t bh = (size_t)(bi * 16 + h);
                #pragma unroll
                for (int nf = 0; nf < 4; nf++) {
                    int d = nf * 16 + cc;               // d within head (wc folded into h)
                    bf16_t v = f2b_rne(acc[mf][nf][j]);
                    if (part == 2) {
                        int lane16 = (d & 31) + 32 * ((seq >> 3) & 1);
                        int ii = (d >> 5) * 2 + ((seq >> 4) & 1);
                        vlin[(((bh * 32 + (seq >> 5)) * 4 + ii) * 64 + lane16) * 8 + (seq & 7)] = v;
                    } else {
                        int lane16 = (seq & 31) + 32 * ((d >> 3) & 1);
                        bf16_t* dst = (part == 0) ? qlin : klin;
                        dst[(((bh * 32 + (seq >> 5)) * 4 + (d >> 4)) * 64 + lane16) * 8 + (d & 7)] = v;
                    }
                }
            }
    }
}

// ---------------------------------------------------------------------------
// Swapped-operand MFMA flash attention. All Q/K/V fragment loads are
// fully-coalesced dwordx4 from fragment-order layouts (qlin/klin/vlin).
// No LDS staging, no barriers in k-loop. K register-double-buffered;
// V issued early. Grid: 1024 blocks (XCD swizzle), 256 thr / 4 waves.
// ---------------------------------------------------------------------------
__global__ __launch_bounds__(256, 3) void attn_mfma4(const bf16_t* __restrict__ qlin,
                                                     const float* __restrict__ tab,
                                                     const bf16_t* __restrict__ klin,
                                                     const bf16_t* __restrict__ vlin,
                                                     bf16_t* __restrict__ attn_out) {
    __shared__ float bias2[2304];
    __shared__ bf16_t Ol[4 * 32 * 68];

    // swizzle decode: i%8 selects XCD; 8 consecutive i>>3 slots = 8 q-chunks of g
    const int i = blockIdx.x;
    const int g = ((i >> 6) << 3) + (i & 7);   // b*16 + h
    const int qc = (i >> 3) & 7;
    const int b = g >> 4, h = g & 15;
    const int q0 = qc * 128;

    const int tid = threadIdx.x;
    const int lane = tid & 63;
    const int w = tid >> 6;
    const int l31 = lane & 31;
    const int hi = lane >> 5;

    const float* tabh = tab + h * 2048;
    const int wbase = 896 - q0;
    #pragma unroll
    for (int it = 0; it < 5; it++) {
        int j = it * 256 + tid;
        if (j < 1151) {
            bias2[2 * j]     = tabh[wbase + j];
            bias2[2 * j + 1] = tabh[wbase + j + 1];
        }
    }

    const bf16_t* ql = qlin + (size_t)g * 65536;
    const bf16_t* kl = klin + (size_t)g * 65536;
    const bf16_t* vl = vlin + (size_t)g * 65536;

    const int qloc = w * 32 + l31;
    const int qt = qc * 4 + w;
    short8 qf[4];
    #pragma unroll
    for (int s = 0; s < 4; s++)
        qf[s] = *(const short8*)(ql + (size_t)qt * 2048 + s * 512 + lane * 8);

    f32x16 O0 = (f32x16)0.f, O1 = (f32x16)0.f;
    float m_run = -1e30f, l_run = 0.f;

    auto loadk = [&](short8 (&dst)[4], int kt) {
        const bf16_t* kp = kl + (size_t)kt * 2048 + lane * 8;
        #pragma unroll
        for (int s = 0; s < 4; s++) dst[s] = *(const short8*)(kp + s * 512);
    };

    auto compute = [&](short8 (&kf)[4], int kt) {
        const int k0 = kt * 32;
        // V fragment loads issued first; consumed after QK^T + softmax
        const bf16_t* vp = vl + (size_t)kt * 2048 + lane * 8;
        short8 vf0 = *(const short8*)vp;
        short8 vf1 = *(const short8*)(vp + 512);
        short8 vf2 = *(const short8*)(vp + 1024);
        short8 vf3 = *(const short8*)(vp + 1536);

        // QK^T (swapped): S^T[kk][q]
        f32x16 S = (f32x16)0.f;
        #pragma unroll
        for (int s = 0; s < 4; s++)
            S = __builtin_amdgcn_mfma_f32_32x32x16_bf16(kf[s], qf[s], S, 0, 0, 0);

        // bias add: reg r -> kk = (r&3) + 8*(r>>2) + 4*hi
        float p[16];
        #pragma unroll
        for (int gg = 0; gg < 4; gg++) {
            int bi = k0 + 8 * gg + 4 * hi + 127 - qloc;
            float2 b0 = *(const float2*)&bias2[2 * bi];
            float2 b1 = *(const float2*)&bias2[2 * (bi + 2)];
            p[4 * gg + 0] = S[4 * gg + 0] + b0.x;
            p[4 * gg + 1] = S[4 * gg + 1] + b0.y;
            p[4 * gg + 2] = S[4 * gg + 2] + b1.x;
            p[4 * gg + 3] = S[4 * gg + 3] + b1.y;
        }

        // online softmax, lane-local stats, defer-max THR=8
        float pmax = p[0];
        #pragma unroll
        for (int r = 1; r < 16; r++) pmax = fmaxf(pmax, p[r]);
        pmax = fmaxf(pmax, __shfl_xor(pmax, 32));
        if (!__all(pmax - m_run <= 8.f)) {
            float mn = fmaxf(m_run, pmax);
            float sc = __expf(m_run - mn);
            l_run *= sc;
            #pragma unroll
            for (int r = 0; r < 16; r++) { O0[r] *= sc; O1[r] *= sc; }
            m_run = mn;
        }
        float rsum = 0.f;
        #pragma unroll
        for (int r = 0; r < 16; r++) { p[r] = __expf(p[r] - m_run); rsum += p[r]; }
        rsum += __shfl_xor(rsum, 32);
        l_run += rsum;

        // pack P to bf16; exchange partner halves to build PV B-frags
        unsigned int wv[8];
        #pragma unroll
        for (int ii = 0; ii < 8; ii++) {
            unsigned int t;
            asm("v_cvt_pk_bf16_f32 %0, %1, %2" : "=v"(t) : "v"(p[2 * ii]), "v"(p[2 * ii + 1]));
            wv[ii] = t;
        }
        unsigned int x0 = __shfl_xor(hi ? wv[0] : wv[2], 32);
        unsigned int x1 = __shfl_xor(hi ? wv[1] : wv[3], 32);
        unsigned int x2 = __shfl_xor(hi ? wv[4] : wv[6], 32);
        unsigned int x3 = __shfl_xor(hi ? wv[5] : wv[7], 32);
        int32x4 pf0i, pf1i;
        if (hi) {
            pf0i = (int32x4){(int)x0, (int)x1, (int)wv[2], (int)wv[3]};
            pf1i = (int32x4){(int)x2, (int)x3, (int)wv[6], (int)wv[7]};
        } else {
            pf0i = (int32x4){(int)wv[0], (int)wv[1], (int)x0, (int)x1};
            pf1i = (int32x4){(int)wv[4], (int)wv[5], (int)x2, (int)x3};
        }
        short8 pf0 = __builtin_bit_cast(short8, pf0i);
        short8 pf1 = __builtin_bit_cast(short8, pf1i);

        // PV (swapped): O^T[d][q] += Vt-frag x P-frag
        O0 = __builtin_amdgcn_mfma_f32_32x32x16_bf16(vf0, pf0, O0, 0, 0, 0);
        O0 = __builtin_amdgcn_mfma_f32_32x32x16_bf16(vf1, pf1, O0, 0, 0, 0);
        O1 = __builtin_amdgcn_mfma_f32_32x32x16_bf16(vf2, pf0, O1, 0, 0, 0);
        O1 = __builtin_amdgcn_mfma_f32_32x32x16_bf16(vf3, pf1, O1, 0, 0, 0);
    };

    __syncthreads();  // bias2 ready

    short8 kA[4], kB[4];
    loadk(kA, 0);
    for (int kt = 0; kt < 32; kt += 2) {
        loadk(kB, kt + 1);
        compute(kA, kt);
        if (kt < 30) loadk(kA, kt + 2);
        compute(kB, kt + 1);
    }

    // epilogue: normalize, LDS-bounce O^T -> row-major, coalesced stores
    float inv = 1.f / l_run;
    bf16_t* olw = &Ol[w * 32 * 68];
    #pragma unroll
    for (int r = 0; r < 16; r++) {
        int dr = (r & 3) + 8 * (r >> 2) + 4 * hi;
        olw[l31 * 68 + dr]      = f2b_rne(O0[r] * inv);
        olw[l31 * 68 + dr + 32] = f2b_rne(O1[r] * inv);
    }
    bf16_t* outp = attn_out + (size_t)(b * 1024 + q0 + w * 32) * 1024 + h * 64;
    #pragma unroll 4
    for (int i2 = 0; i2 < 32; i2++)
        outp[(size_t)i2 * 1024 + lane] = olw[i2 * 68 + lane];
}

// ---------------------------------------------------------------------------
extern "C" void kernel_launch(void* const* d_in, const int* in_sizes, int n_in,
                              void* d_out, int out_size, void* d_ws, size_t ws_size,
                              hipStream_t stream) {
    const float* hs   = (const float*)d_in[0];  // [8,1024,1024]
    const float* wqkv = (const float*)d_in[1];  // [3072,1024]
    const float* emb  = (const float*)d_in[2];  // [32,16]
    const float* wout = (const float*)d_in[3];  // [1024,1024]
    float* out = (float*)d_out;                 // [8,1024,1024] fp32

    char* p = (char*)d_ws;
    bf16_t* hsb   = (bf16_t*)p; p += (size_t)8192 * 1024 * 2;  // 16 MB
    bf16_t* wqkvb = (bf16_t*)p; p += (size_t)3072 * 1024 * 2;  //  6 MB
    bf16_t* woutb = (bf16_t*)p; p += (size_t)1024 * 1024 * 2;  //  2 MB
    bf16_t* qlin  = (bf16_t*)p; p += (size_t)128 * 65536 * 2;  // 16 MB
    bf16_t* klin  = (bf16_t*)p; p += (size_t)128 * 65536 * 2;  // 16 MB
    bf16_t* vlin  = (bf16_t*)p; p += (size_t)128 * 65536 * 2;  // 16 MB
    bf16_t* attnb = (bf16_t*)p; p += (size_t)8192 * 1024 * 2;  // 16 MB
    float*  tab   = (float*)p;                                 // 128 KB

    f2b_kernel<<<2048, 256, 0, stream>>>(hs, hsb, 8192 * 1024 / 4);
    f2b_kernel<<<768, 256, 0, stream>>>(wqkv, wqkvb, 3072 * 1024 / 4);
    f2b_kernel<<<256, 256, 0, stream>>>(wout, woutb, 1024 * 1024 / 4);
    build_bias_tab<<<8, 256, 0, stream>>>(emb, tab);

    gemm_mfma<1, bf16_t><<<1536, 256, 0, stream>>>(hsb, wqkvb, (bf16_t*)nullptr, 3072, 24,
                                                   qlin, klin, vlin);
    attn_mfma4<<<1024, 256, 0, stream>>>(qlin, tab, klin, vlin, attnb);
    gemm_mfma<0, float><<<512, 256, 0, stream>>>(attnb, woutb, out, 1024, 8,
                                                 nullptr, nullptr, nullptr);
}

// Round 8
// 249.117 us; speedup vs baseline: 1.0455x; 1.0455x over previous
//
#include <hip/hip_runtime.h>
#include <math.h>

typedef __attribute__((ext_vector_type(8))) short short8;
typedef __attribute__((ext_vector_type(4))) float f32x4;
typedef __attribute__((ext_vector_type(16))) float f32x16;
typedef __attribute__((ext_vector_type(4))) int int32x4;
typedef unsigned short bf16_t;

#define GLOAD_LDS16(g, l)                                                   \
    __builtin_amdgcn_global_load_lds(                                       \
        (__attribute__((address_space(1))) void*)(g),                       \
        (__attribute__((address_space(3))) void*)(l), 16, 0, 0)

__device__ __forceinline__ bf16_t f2b_rne(float f) {
    unsigned int u = __float_as_uint(f);
    u += 0x7FFFu + ((u >> 16) & 1u);
    return (bf16_t)(u >> 16);
}

// ---------------------------------------------------------------------------
// fp32 -> bf16 conversion
// ---------------------------------------------------------------------------
__global__ __launch_bounds__(256) void f2b_kernel(const float* __restrict__ in,
                                                  bf16_t* __restrict__ out, int n4) {
    int stride = gridDim.x * 256;
    for (int i = blockIdx.x * 256 + threadIdx.x; i < n4; i += stride) {
        float4 v = ((const float4*)in)[i];
        ushort4 p;
        p.x = f2b_rne(v.x); p.y = f2b_rne(v.y);
        p.z = f2b_rne(v.z); p.w = f2b_rne(v.w);
        ((ushort4*)out)[i] = p;
    }
}

// ---------------------------------------------------------------------------
// Relative-position bias table: tab[h][(k-q)+1023]  (validated round 2)
// ---------------------------------------------------------------------------
__global__ void build_bias_tab(const float* __restrict__ emb, float* __restrict__ tab) {
    int idx = blockIdx.x * 256 + threadIdx.x;
    if (idx >= 2047) return;
    int rel = idx - 1023;
    int rb = rel > 0 ? 16 : 0;
    int rp = rel < 0 ? -rel : rel;
    int bucket;
    if (rp < 8) {
        bucket = rb + rp;
    } else {
        float t = logf((float)rp * 0.125f);
        int vi = 8 + (int)(t / 2.772588722239781f * 8.0f);
        bucket = rb + (vi < 15 ? vi : 15);
    }
    #pragma unroll
    for (int hh = 0; hh < 16; hh++)
        tab[hh * 2048 + idx] = emb[bucket * 16 + hh];
}

// ---------------------------------------------------------------------------
// bf16 MFMA GEMM, 128x128 tile, BK=32, XCD swizzle, conflict-free LDS
// (stage-side pre-swizzle of source col + same XOR on read — validated r7).
// MODE 0: row-major OT output.
// MODE 1: QKV -> MFMA fragment layouts via LDS-bounce epilogue (coalesced):
//   qlin/klin[bh][t][s][lane][j] = X[seq = t*32+(lane&31)][d = 16s+8(lane>>5)+j]
//   vlin[bh][t][i][lane][j]      = V[seq = t*32+16(i&1)+8(lane>>5)+j][d=(lane&31)+32(i>>1)]
// ---------------------------------------------------------------------------
template <int MODE, typename OT>
__global__ __launch_bounds__(256) void gemm_mfma(const bf16_t* __restrict__ A,
                                                 const bf16_t* __restrict__ B,
                                                 OT* __restrict__ C, int N, int gx,
                                                 bf16_t* __restrict__ qlin,
                                                 bf16_t* __restrict__ klin,
                                                 bf16_t* __restrict__ vlin) {
    __shared__ __align__(16) bf16_t As[128 * 32];
    __shared__ __align__(16) bf16_t Bs[128 * 32];
    const int nwg = gridDim.x;
    const int cpx = nwg >> 3;
    const int swz = (blockIdx.x & 7) * cpx + (blockIdx.x >> 3);
    const int bx = swz % gx, by = swz / gx;

    const int tid = threadIdx.x;
    const int lane = tid & 63;
    const int wv = tid >> 6;
    const int wr = wv >> 1, wc = wv & 1;
    const int m0 = by * 128, n0 = bx * 128;
    const int cc = lane & 15, cg = lane >> 4;

    f32x4 acc[4][4];
    #pragma unroll
    for (int i = 0; i < 4; i++)
        #pragma unroll
        for (int j = 0; j < 4; j++) acc[i][j] = {0.f, 0.f, 0.f, 0.f};

    const int rsw = (cc >> 1) & 3;  // read-side XOR term

    for (int k0 = 0; k0 < 1024; k0 += 32) {
        __syncthreads();
        #pragma unroll
        for (int it = 0; it < 2; it++) {
            int c = it * 256 + tid;
            int r = c >> 2, sl = c & 3;
            int kc = (sl ^ ((r >> 1) & 3)) * 8;    // pre-swizzled source col
            GLOAD_LDS16(A + (size_t)(m0 + r) * 1024 + k0 + kc, &As[c * 8]);
            GLOAD_LDS16(B + (size_t)(n0 + r) * 1024 + k0 + kc, &Bs[c * 8]);
        }
        __syncthreads();

        short8 af[4], bf[4];
        #pragma unroll
        for (int mf = 0; mf < 4; mf++)
            af[mf] = *(const short8*)&As[(wr * 64 + mf * 16 + cc) * 32 + (cg ^ rsw) * 8];
        #pragma unroll
        for (int nf = 0; nf < 4; nf++)
            bf[nf] = *(const short8*)&Bs[(wc * 64 + nf * 16 + cc) * 32 + (cg ^ rsw) * 8];
        #pragma unroll
        for (int mf = 0; mf < 4; mf++)
            #pragma unroll
            for (int nf = 0; nf < 4; nf++)
                acc[mf][nf] = __builtin_amdgcn_mfma_f32_16x16x32_bf16(
                    af[mf], bf[nf], acc[mf][nf], 0, 0, 0);
    }

    if constexpr (MODE == 0) {
        #pragma unroll
        for (int mf = 0; mf < 4; mf++)
            #pragma unroll
            for (int j = 0; j < 4; j++) {
                size_t row = (size_t)(m0 + wr * 64 + mf * 16 + cg * 4 + j);
                OT* cp = C + row * N + n0 + wc * 64 + cc;
                #pragma unroll
                for (int nf = 0; nf < 4; nf++) cp[nf * 16] = acc[mf][nf][j];
            }
    } else {
        // LDS-bounce epilogue: two 64-row halves; coalesced fragment stores
        __shared__ bf16_t Es[64 * 136];
        const int part = n0 >> 10;                      // 0=q 1=k 2=v
        const int hbase = (n0 & 1023) >> 6;             // head pair base
        const int bI = m0 >> 10;                        // batch index
        const int seq0 = m0 & 1023;

        for (int half = 0; half < 2; half++) {
            __syncthreads();
            if (wr == half) {
                #pragma unroll
                for (int mf = 0; mf < 4; mf++)
                    #pragma unroll
                    for (int j = 0; j < 4; j++) {
                        int rl = mf * 16 + cg * 4 + j;
                        #pragma unroll
                        for (int nf = 0; nf < 4; nf++)
                            Es[rl * 136 + wc * 64 + nf * 16 + cc] = f2b_rne(acc[mf][nf][j]);
                    }
            }
            __syncthreads();
            const int th = (seq0 + half * 64) >> 5;     // base t index for this half
            #pragma unroll
            for (int it = 0; it < 4; it++) {
                int g = it * 256 + tid;
                int hh = g >> 9, t2 = (g >> 8) & 1, ii = (g >> 6) & 3, l16 = g & 63;
                size_t bh = (size_t)(bI * 16 + hbase + hh);
                if (part == 2) {
                    int d = (ii >> 1) * 32 + (l16 & 31);
                    int sb = t2 * 32 + (ii & 1) * 16 + (l16 >> 5) * 8;
                    short8 v;
                    #pragma unroll
                    for (int j = 0; j < 8; j++)
                        v[j] = (short)Es[(sb + j) * 136 + hh * 64 + d];
                    *(short8*)(vlin + (((bh * 32 + th + t2) * 4 + ii) * 64 + l16) * 8) = v;
                } else {
                    int row = t2 * 32 + (l16 & 31);
                    int d0 = ii * 16 + (l16 >> 5) * 8;
                    short8 v = *(const short8*)&Es[row * 136 + hh * 64 + d0];
                    bf16_t* dst = (part == 0) ? qlin : klin;
                    *(short8*)(dst + (((bh * 32 + th + t2) * 4 + ii) * 64 + l16) * 8) = v;
                }
            }
        }
    }
}

// ---------------------------------------------------------------------------
// Swapped-operand MFMA flash attention (unchanged from round 7 — validated).
// ---------------------------------------------------------------------------
__global__ __launch_bounds__(256, 3) void attn_mfma4(const bf16_t* __restrict__ qlin,
                                                     const float* __restrict__ tab,
                                                     const bf16_t* __restrict__ klin,
                                                     const bf16_t* __restrict__ vlin,
                                                     bf16_t* __restrict__ attn_out) {
    __shared__ float bias2[2304];
    __shared__ bf16_t Ol[4 * 32 * 68];

    const int i = blockIdx.x;
    const int g = ((i >> 6) << 3) + (i & 7);   // b*16 + h
    const int qc = (i >> 3) & 7;
    const int b = g >> 4, h = g & 15;
    const int q0 = qc * 128;

    const int tid = threadIdx.x;
    const int lane = tid & 63;
    const int w = tid >> 6;
    const int l31 = lane & 31;
    const int hi = lane >> 5;

    const float* tabh = tab + h * 2048;
    const int wbase = 896 - q0;
    #pragma unroll
    for (int it = 0; it < 5; it++) {
        int j = it * 256 + tid;
        if (j < 1151) {
            bias2[2 * j]     = tabh[wbase + j];
            bias2[2 * j + 1] = tabh[wbase + j + 1];
        }
    }

    const bf16_t* ql = qlin + (size_t)g * 65536;
    const bf16_t* kl = klin + (size_t)g * 65536;
    const bf16_t* vl = vlin + (size_t)g * 65536;

    const int qloc = w * 32 + l31;
    const int qt = qc * 4 + w;
    short8 qf[4];
    #pragma unroll
    for (int s = 0; s < 4; s++)
        qf[s] = *(const short8*)(ql + (size_t)qt * 2048 + s * 512 + lane * 8);

    f32x16 O0 = (f32x16)0.f, O1 = (f32x16)0.f;
    float m_run = -1e30f, l_run = 0.f;

    auto loadk = [&](short8 (&dst)[4], int kt) {
        const bf16_t* kp = kl + (size_t)kt * 2048 + lane * 8;
        #pragma unroll
        for (int s = 0; s < 4; s++) dst[s] = *(const short8*)(kp + s * 512);
    };

    auto compute = [&](short8 (&kf)[4], int kt) {
        const int k0 = kt * 32;
        const bf16_t* vp = vl + (size_t)kt * 2048 + lane * 8;
        short8 vf0 = *(const short8*)vp;
        short8 vf1 = *(const short8*)(vp + 512);
        short8 vf2 = *(const short8*)(vp + 1024);
        short8 vf3 = *(const short8*)(vp + 1536);

        f32x16 S = (f32x16)0.f;
        #pragma unroll
        for (int s = 0; s < 4; s++)
            S = __builtin_amdgcn_mfma_f32_32x32x16_bf16(kf[s], qf[s], S, 0, 0, 0);

        float p[16];
        #pragma unroll
        for (int gg = 0; gg < 4; gg++) {
            int bi = k0 + 8 * gg + 4 * hi + 127 - qloc;
            float2 b0 = *(const float2*)&bias2[2 * bi];
            float2 b1 = *(const float2*)&bias2[2 * (bi + 2)];
            p[4 * gg + 0] = S[4 * gg + 0] + b0.x;
            p[4 * gg + 1] = S[4 * gg + 1] + b0.y;
            p[4 * gg + 2] = S[4 * gg + 2] + b1.x;
            p[4 * gg + 3] = S[4 * gg + 3] + b1.y;
        }

        float pmax = p[0];
        #pragma unroll
        for (int r = 1; r < 16; r++) pmax = fmaxf(pmax, p[r]);
        pmax = fmaxf(pmax, __shfl_xor(pmax, 32));
        if (!__all(pmax - m_run <= 8.f)) {
            float mn = fmaxf(m_run, pmax);
            float sc = __expf(m_run - mn);
            l_run *= sc;
            #pragma unroll
            for (int r = 0; r < 16; r++) { O0[r] *= sc; O1[r] *= sc; }
            m_run = mn;
        }
        float rsum = 0.f;
        #pragma unroll
        for (int r = 0; r < 16; r++) { p[r] = __expf(p[r] - m_run); rsum += p[r]; }
        rsum += __shfl_xor(rsum, 32);
        l_run += rsum;

        unsigned int wv[8];
        #pragma unroll
        for (int ii = 0; ii < 8; ii++) {
            unsigned int t;
            asm("v_cvt_pk_bf16_f32 %0, %1, %2" : "=v"(t) : "v"(p[2 * ii]), "v"(p[2 * ii + 1]));
            wv[ii] = t;
        }
        unsigned int x0 = __shfl_xor(hi ? wv[0] : wv[2], 32);
        unsigned int x1 = __shfl_xor(hi ? wv[1] : wv[3], 32);
        unsigned int x2 = __shfl_xor(hi ? wv[4] : wv[6], 32);
        unsigned int x3 = __shfl_xor(hi ? wv[5] : wv[7], 32);
        int32x4 pf0i, pf1i;
        if (hi) {
            pf0i = (int32x4){(int)x0, (int)x1, (int)wv[2], (int)wv[3]};
            pf1i = (int32x4){(int)x2, (int)x3, (int)wv[6], (int)wv[7]};
        } else {
            pf0i = (int32x4){(int)wv[0], (int)wv[1], (int)x0, (int)x1};
            pf1i = (int32x4){(int)wv[4], (int)wv[5], (int)x2, (int)x3};
        }
        short8 pf0 = __builtin_bit_cast(short8, pf0i);
        short8 pf1 = __builtin_bit_cast(short8, pf1i);

        O0 = __builtin_amdgcn_mfma_f32_32x32x16_bf16(vf0, pf0, O0, 0, 0, 0);
        O0 = __builtin_amdgcn_mfma_f32_32x32x16_bf16(vf1, pf1, O0, 0, 0, 0);
        O1 = __builtin_amdgcn_mfma_f32_32x32x16_bf16(vf2, pf0, O1, 0, 0, 0);
        O1 = __builtin_amdgcn_mfma_f32_32x32x16_bf16(vf3, pf1, O1, 0, 0, 0);
    };

    __syncthreads();  // bias2 ready

    short8 kA[4], kB[4];
    loadk(kA, 0);
    for (int kt = 0; kt < 32; kt += 2) {
        loadk(kB, kt + 1);
        compute(kA, kt);
        if (kt < 30) loadk(kA, kt + 2);
        compute(kB, kt + 1);
    }

    float inv = 1.f / l_run;
    bf16_t* olw = &Ol[w * 32 * 68];
    #pragma unroll
    for (int r = 0; r < 16; r++) {
        int dr = (r & 3) + 8 * (r >> 2) + 4 * hi;
        olw[l31 * 68 + dr]      = f2b_rne(O0[r] * inv);
        olw[l31 * 68 + dr + 32] = f2b_rne(O1[r] * inv);
    }
    bf16_t* outp = attn_out + (size_t)(b * 1024 + q0 + w * 32) * 1024 + h * 64;
    #pragma unroll 4
    for (int i2 = 0; i2 < 32; i2++)
        outp[(size_t)i2 * 1024 + lane] = olw[i2 * 68 + lane];
}

// ---------------------------------------------------------------------------
extern "C" void kernel_launch(void* const* d_in, const int* in_sizes, int n_in,
                              void* d_out, int out_size, void* d_ws, size_t ws_size,
                              hipStream_t stream) {
    const float* hs   = (const float*)d_in[0];  // [8,1024,1024]
    const float* wqkv = (const float*)d_in[1];  // [3072,1024]
    const float* emb  = (const float*)d_in[2];  // [32,16]
    const float* wout = (const float*)d_in[3];  // [1024,1024]
    float* out = (float*)d_out;                 // [8,1024,1024] fp32

    char* p = (char*)d_ws;
    bf16_t* hsb   = (bf16_t*)p; p += (size_t)8192 * 1024 * 2;  // 16 MB
    bf16_t* wqkvb = (bf16_t*)p; p += (size_t)3072 * 1024 * 2;  //  6 MB
    bf16_t* woutb = (bf16_t*)p; p += (size_t)1024 * 1024 * 2;  //  2 MB
    bf16_t* qlin  = (bf16_t*)p; p += (size_t)128 * 65536 * 2;  // 16 MB
    bf16_t* klin  = (bf16_t*)p; p += (size_t)128 * 65536 * 2;  // 16 MB
    bf16_t* vlin  = (bf16_t*)p; p += (size_t)128 * 65536 * 2;  // 16 MB
    bf16_t* attnb = (bf16_t*)p; p += (size_t)8192 * 1024 * 2;  // 16 MB
    float*  tab   = (float*)p;                                 // 128 KB

    f2b_kernel<<<2048, 256, 0, stream>>>(hs, hsb, 8192 * 1024 / 4);
    f2b_kernel<<<768, 256, 0, stream>>>(wqkv, wqkvb, 3072 * 1024 / 4);
    f2b_kernel<<<256, 256, 0, stream>>>(wout, woutb, 1024 * 1024 / 4);
    build_bias_tab<<<8, 256, 0, stream>>>(emb, tab);

    gemm_mfma<1, bf16_t><<<1536, 256, 0, stream>>>(hsb, wqkvb, (bf16_t*)nullptr, 3072, 24,
                                                   qlin, klin, vlin);
    attn_mfma4<<<1024, 256, 0, stream>>>(qlin, tab, klin, vlin, attnb);
    gemm_mfma<0, float><<<512, 256, 0, stream>>>(attnb, woutb, out, 1024, 8,
                                                 nullptr, nullptr, nullptr);
}

// Round 10
// 246.701 us; speedup vs baseline: 1.0558x; 1.0098x over previous
//
#include <hip/hip_runtime.h>
#include <math.h>

typedef __attribute__((ext_vector_type(8))) short short8;
typedef __attribute__((ext_vector_type(4))) float f32x4;
typedef __attribute__((ext_vector_type(16))) float f32x16;
typedef __attribute__((ext_vector_type(4))) int int32x4;
typedef unsigned short bf16_t;

#define L2E 1.44269504089f

#define GLOAD_LDS16(g, l)                                                   \
    __builtin_amdgcn_global_load_lds(                                       \
        (__attribute__((address_space(1))) void*)(g),                       \
        (__attribute__((address_space(3))) void*)(l), 16, 0, 0)

__device__ __forceinline__ bf16_t f2b_rne(float f) {
    unsigned int u = __float_as_uint(f);
    u += 0x7FFFu + ((u >> 16) & 1u);
    return (bf16_t)(u >> 16);
}

__device__ __forceinline__ float max3f(float a, float b, float c) {
    float d;
    asm("v_max3_f32 %0, %1, %2, %3" : "=v"(d) : "v"(a), "v"(b), "v"(c));
    return d;
}

__device__ __forceinline__ float exp2_fast(float x) {
    float r;
    asm("v_exp_f32 %0, %1" : "=v"(r) : "v"(x));
    return r;
}

// ---------------------------------------------------------------------------
// fp32 -> bf16 conversion
// ---------------------------------------------------------------------------
__global__ __launch_bounds__(256) void f2b_kernel(const float* __restrict__ in,
                                                  bf16_t* __restrict__ out, int n4) {
    int stride = gridDim.x * 256;
    for (int i = blockIdx.x * 256 + threadIdx.x; i < n4; i += stride) {
        float4 v = ((const float4*)in)[i];
        ushort4 p;
        p.x = f2b_rne(v.x); p.y = f2b_rne(v.y);
        p.z = f2b_rne(v.z); p.w = f2b_rne(v.w);
        ((ushort4*)out)[i] = p;
    }
}

// ---------------------------------------------------------------------------
// Relative-position bias table: tab[h][(k-q)+1023], PRE-SCALED by log2(e).
// Softmax runs in exp2 domain: p = fma(S, log2e, bias') = log2e*(S + bias).
// ---------------------------------------------------------------------------
__global__ void build_bias_tab(const float* __restrict__ emb, float* __restrict__ tab) {
    int idx = blockIdx.x * 256 + threadIdx.x;
    if (idx >= 2047) return;
    int rel = idx - 1023;
    int rb = rel > 0 ? 16 : 0;
    int rp = rel < 0 ? -rel : rel;
    int bucket;
    if (rp < 8) {
        bucket = rb + rp;
    } else {
        float t = logf((float)rp * 0.125f);
        int vi = 8 + (int)(t / 2.772588722239781f * 8.0f);
        bucket = rb + (vi < 15 ? vi : 15);
    }
    #pragma unroll
    for (int hh = 0; hh < 16; hh++)
        tab[hh * 2048 + idx] = emb[bucket * 16 + hh] * L2E;
}

// ---------------------------------------------------------------------------
// bf16 MFMA GEMM, 128x128 tile, BK=64 (halved barrier count vs BK=32),
// XCD swizzle, conflict-free LDS via granule XOR (stage col = (sl^(r&7))*8,
// read XOR cc&7 — both-sides involution; r7-validated discipline).
// MODE 0: row-major OT output.
// MODE 1: QKV -> MFMA fragment layouts via LDS-bounce epilogue (Es unions
//         with As/Bs — epilogue-only liveness).
//   qlin/klin[bh][t][s][lane][j] = X[seq = t*32+(lane&31)][d = 16s+8(lane>>5)+j]
//   vlin[bh][t][i][lane][j]      = V[seq = t*32+16(i&1)+8(lane>>5)+j][d=(lane&31)+32(i>>1)]
// ---------------------------------------------------------------------------
template <int MODE, typename OT>
__global__ __launch_bounds__(256) void gemm_mfma(const bf16_t* __restrict__ A,
                                                 const bf16_t* __restrict__ B,
                                                 OT* __restrict__ C, int N, int gx,
                                                 bf16_t* __restrict__ qlin,
                                                 bf16_t* __restrict__ klin,
                                                 bf16_t* __restrict__ vlin) {
    __shared__ __align__(16) char smem[32768];
    bf16_t* As = (bf16_t*)smem;              // [128][64]
    bf16_t* Bs = (bf16_t*)(smem + 16384);    // [128][64]

    const int nwg = gridDim.x;
    const int cpx = nwg >> 3;
    const int swz = (blockIdx.x & 7) * cpx + (blockIdx.x >> 3);
    const int bx = swz % gx, by = swz / gx;

    const int tid = threadIdx.x;
    const int lane = tid & 63;
    const int wv = tid >> 6;
    const int wr = wv >> 1, wc = wv & 1;
    const int m0 = by * 128, n0 = bx * 128;
    const int cc = lane & 15, cg = lane >> 4;

    f32x4 acc[4][4];
    #pragma unroll
    for (int i = 0; i < 4; i++)
        #pragma unroll
        for (int j = 0; j < 4; j++) acc[i][j] = {0.f, 0.f, 0.f, 0.f};

    const int rsw = cc & 7;  // read-side XOR (fragment row & 7 == cc & 7)

    for (int k0 = 0; k0 < 1024; k0 += 64) {
        __syncthreads();
        #pragma unroll
        for (int it = 0; it < 4; it++) {
            int c = it * 256 + tid;               // 0..1023 granules
            int r = c >> 3, sl = c & 7;
            int kc = (sl ^ (r & 7)) * 8;          // pre-swizzled source col
            GLOAD_LDS16(A + (size_t)(m0 + r) * 1024 + k0 + kc, &As[c * 8]);
            GLOAD_LDS16(B + (size_t)(n0 + r) * 1024 + k0 + kc, &Bs[c * 8]);
        }
        __syncthreads();

        #pragma unroll
        for (int h = 0; h < 2; h++) {
            short8 af[4], bf[4];
            #pragma unroll
            for (int mf = 0; mf < 4; mf++)
                af[mf] = *(const short8*)&As[(wr * 64 + mf * 16 + cc) * 64 +
                                             ((h * 4 + cg) ^ rsw) * 8];
            #pragma unroll
            for (int nf = 0; nf < 4; nf++)
                bf[nf] = *(const short8*)&Bs[(wc * 64 + nf * 16 + cc) * 64 +
                                             ((h * 4 + cg) ^ rsw) * 8];
            #pragma unroll
            for (int mf = 0; mf < 4; mf++)
                #pragma unroll
                for (int nf = 0; nf < 4; nf++)
                    acc[mf][nf] = __builtin_amdgcn_mfma_f32_16x16x32_bf16(
                        af[mf], bf[nf], acc[mf][nf], 0, 0, 0);
        }
    }

    if constexpr (MODE == 0) {
        #pragma unroll
        for (int mf = 0; mf < 4; mf++)
            #pragma unroll
            for (int j = 0; j < 4; j++) {
                size_t row = (size_t)(m0 + wr * 64 + mf * 16 + cg * 4 + j);
                OT* cp = C + row * N + n0 + wc * 64 + cc;
                #pragma unroll
                for (int nf = 0; nf < 4; nf++) cp[nf * 16] = acc[mf][nf][j];
            }
    } else {
        // LDS-bounce epilogue (Es aliases As/Bs): two 64-row halves
        bf16_t* Es = (bf16_t*)smem;              // [64][136]
        const int part = n0 >> 10;               // 0=q 1=k 2=v
        const int hbase = (n0 & 1023) >> 6;
        const int bI = m0 >> 10;
        const int seq0 = m0 & 1023;

        for (int half = 0; half < 2; half++) {
            __syncthreads();
            if (wr == half) {
                #pragma unroll
                for (int mf = 0; mf < 4; mf++)
                    #pragma unroll
                    for (int j = 0; j < 4; j++) {
                        int rl = mf * 16 + cg * 4 + j;
                        #pragma unroll
                        for (int nf = 0; nf < 4; nf++)
                            Es[rl * 136 + wc * 64 + nf * 16 + cc] =
                                f2b_rne(acc[mf][nf][j]);
                    }
            }
            __syncthreads();
            const int th = (seq0 + half * 64) >> 5;
            #pragma unroll
            for (int it = 0; it < 4; it++) {
                int g = it * 256 + tid;
                int hh = g >> 9, t2 = (g >> 8) & 1, ii = (g >> 6) & 3, l16 = g & 63;
                size_t bh = (size_t)(bI * 16 + hbase + hh);
                if (part == 2) {
                    int d = (ii >> 1) * 32 + (l16 & 31);
                    int sb = t2 * 32 + (ii & 1) * 16 + (l16 >> 5) * 8;
                    short8 v;
                    #pragma unroll
                    for (int j = 0; j < 8; j++)
                        v[j] = (short)Es[(sb + j) * 136 + hh * 64 + d];
                    *(short8*)(vlin + (((bh * 32 + th + t2) * 4 + ii) * 64 + l16) * 8) = v;
                } else {
                    int row = t2 * 32 + (l16 & 31);
                    int d0 = ii * 16 + (l16 >> 5) * 8;
                    short8 v = *(const short8*)&Es[row * 136 + hh * 64 + d0];
                    bf16_t* dst = (part == 0) ? qlin : klin;
                    *(short8*)(dst + (((bh * 32 + th + t2) * 4 + ii) * 64 + l16) * 8) = v;
                }
            }
        }
    }
}

// ---------------------------------------------------------------------------
// Swapped-operand MFMA flash attention; softmax in exp2 domain via
// p = fma(S, log2e, bias') — no extra Q rounding. max3/sum trees.
// ---------------------------------------------------------------------------
__global__ __launch_bounds__(256, 3) void attn_mfma4(const bf16_t* __restrict__ qlin,
                                                     const float* __restrict__ tab,
                                                     const bf16_t* __restrict__ klin,
                                                     const bf16_t* __restrict__ vlin,
                                                     bf16_t* __restrict__ attn_out) {
    __shared__ float bias2[2304];
    __shared__ bf16_t Ol[4 * 32 * 68];

    const int i = blockIdx.x;
    const int g = ((i >> 6) << 3) + (i & 7);   // b*16 + h
    const int qc = (i >> 3) & 7;
    const int b = g >> 4, h = g & 15;
    const int q0 = qc * 128;

    const int tid = threadIdx.x;
    const int lane = tid & 63;
    const int w = tid >> 6;
    const int l31 = lane & 31;
    const int hi = lane >> 5;

    const float* tabh = tab + h * 2048;
    const int wbase = 896 - q0;
    #pragma unroll
    for (int it = 0; it < 5; it++) {
        int j = it * 256 + tid;
        if (j < 1151) {
            bias2[2 * j]     = tabh[wbase + j];
            bias2[2 * j + 1] = tabh[wbase + j + 1];
        }
    }

    const bf16_t* ql = qlin + (size_t)g * 65536;
    const bf16_t* kl = klin + (size_t)g * 65536;
    const bf16_t* vl = vlin + (size_t)g * 65536;

    const int qloc = w * 32 + l31;
    const int qt = qc * 4 + w;
    short8 qf[4];
    #pragma unroll
    for (int s = 0; s < 4; s++)
        qf[s] = *(const short8*)(ql + (size_t)qt * 2048 + s * 512 + lane * 8);

    f32x16 O0 = (f32x16)0.f, O1 = (f32x16)0.f;
    float m_run = -1e30f, l_run = 0.f;

    auto loadk = [&](short8 (&dst)[4], int kt) {
        const bf16_t* kp = kl + (size_t)kt * 2048 + lane * 8;
        #pragma unroll
        for (int s = 0; s < 4; s++) dst[s] = *(const short8*)(kp + s * 512);
    };

    auto compute = [&](short8 (&kf)[4], int kt) {
        const int k0 = kt * 32;
        const bf16_t* vp = vl + (size_t)kt * 2048 + lane * 8;
        short8 vf0 = *(const short8*)vp;
        short8 vf1 = *(const short8*)(vp + 512);
        short8 vf2 = *(const short8*)(vp + 1024);
        short8 vf3 = *(const short8*)(vp + 1536);

        f32x16 S = (f32x16)0.f;
        #pragma unroll
        for (int s = 0; s < 4; s++)
            S = __builtin_amdgcn_mfma_f32_32x32x16_bf16(kf[s], qf[s], S, 0, 0, 0);

        float p[16];
        #pragma unroll
        for (int gg = 0; gg < 4; gg++) {
            int bi = k0 + 8 * gg + 4 * hi + 127 - qloc;
            float2 b0 = *(const float2*)&bias2[2 * bi];
            float2 b1 = *(const float2*)&bias2[2 * (bi + 2)];
            p[4 * gg + 0] = fmaf(S[4 * gg + 0], L2E, b0.x);
            p[4 * gg + 1] = fmaf(S[4 * gg + 1], L2E, b0.y);
            p[4 * gg + 2] = fmaf(S[4 * gg + 2], L2E, b1.x);
            p[4 * gg + 3] = fmaf(S[4 * gg + 3], L2E, b1.y);
        }

        // max tree (depth 3), exp2 domain
        float t0 = max3f(p[0], p[1], p[2]);
        float t1 = max3f(p[3], p[4], p[5]);
        float t2 = max3f(p[6], p[7], p[8]);
        float t3 = max3f(p[9], p[10], p[11]);
        float t4 = max3f(p[12], p[13], p[14]);
        float u0 = max3f(t0, t1, p[15]);
        float pmax = fmaxf(u0, max3f(t2, t3, t4));
        pmax = fmaxf(pmax, __shfl_xor(pmax, 32));
        if (!__all(pmax - m_run <= 8.f)) {
            float mn = fmaxf(m_run, pmax);
            float sc = exp2_fast(m_run - mn);
            l_run *= sc;
            #pragma unroll
            for (int r = 0; r < 16; r++) { O0[r] *= sc; O1[r] *= sc; }
            m_run = mn;
        }
        #pragma unroll
        for (int r = 0; r < 16; r++) p[r] = exp2_fast(p[r] - m_run);
        // pairwise sum tree
        float s0 = (p[0] + p[1]) + (p[2] + p[3]);
        float s1 = (p[4] + p[5]) + (p[6] + p[7]);
        float s2 = (p[8] + p[9]) + (p[10] + p[11]);
        float s3 = (p[12] + p[13]) + (p[14] + p[15]);
        float rsum = (s0 + s1) + (s2 + s3);
        rsum += __shfl_xor(rsum, 32);
        l_run += rsum;

        unsigned int wvv[8];
        #pragma unroll
        for (int ii = 0; ii < 8; ii++) {
            unsigned int t;
            asm("v_cvt_pk_bf16_f32 %0, %1, %2" : "=v"(t) : "v"(p[2 * ii]), "v"(p[2 * ii + 1]));
            wvv[ii] = t;
        }
        unsigned int x0 = __shfl_xor(hi ? wvv[0] : wvv[2], 32);
        unsigned int x1 = __shfl_xor(hi ? wvv[1] : wvv[3], 32);
        unsigned int x2 = __shfl_xor(hi ? wvv[4] : wvv[6], 32);
        unsigned int x3 = __shfl_xor(hi ? wvv[5] : wvv[7], 32);
        int32x4 pf0i, pf1i;
        if (hi) {
            pf0i = (int32x4){(int)x0, (int)x1, (int)wvv[2], (int)wvv[3]};
            pf1i = (int32x4){(int)x2, (int)x3, (int)wvv[6], (int)wvv[7]};
        } else {
            pf0i = (int32x4){(int)wvv[0], (int)wvv[1], (int)x0, (int)x1};
            pf1i = (int32x4){(int)wvv[4], (int)wvv[5], (int)x2, (int)x3};
        }
        short8 pf0 = __builtin_bit_cast(short8, pf0i);
        short8 pf1 = __builtin_bit_cast(short8, pf1i);

        O0 = __builtin_amdgcn_mfma_f32_32x32x16_bf16(vf0, pf0, O0, 0, 0, 0);
        O0 = __builtin_amdgcn_mfma_f32_32x32x16_bf16(vf1, pf1, O0, 0, 0, 0);
        O1 = __builtin_amdgcn_mfma_f32_32x32x16_bf16(vf2, pf0, O1, 0, 0, 0);
        O1 = __builtin_amdgcn_mfma_f32_32x32x16_bf16(vf3, pf1, O1, 0, 0, 0);
    };

    __syncthreads();  // bias2 ready

    short8 kA[4], kB[4];
    loadk(kA, 0);
    for (int kt = 0; kt < 32; kt += 2) {
        loadk(kB, kt + 1);
        compute(kA, kt);
        if (kt < 30) loadk(kA, kt + 2);
        compute(kB, kt + 1);
    }

    float inv = 1.f / l_run;
    bf16_t* olw = &Ol[w * 32 * 68];
    #pragma unroll
    for (int r = 0; r < 16; r++) {
        int dr = (r & 3) + 8 * (r >> 2) + 4 * hi;
        olw[l31 * 68 + dr]      = f2b_rne(O0[r] * inv);
        olw[l31 * 68 + dr + 32] = f2b_rne(O1[r] * inv);
    }
    bf16_t* outp = attn_out + (size_t)(b * 1024 + q0 + w * 32) * 1024 + h * 64;
    #pragma unroll 4
    for (int i2 = 0; i2 < 32; i2++)
        outp[(size_t)i2 * 1024 + lane] = olw[i2 * 68 + lane];
}

// ---------------------------------------------------------------------------
extern "C" void kernel_launch(void* const* d_in, const int* in_sizes, int n_in,
                              void* d_out, int out_size, void* d_ws, size_t ws_size,
                              hipStream_t stream) {
    const float* hs   = (const float*)d_in[0];  // [8,1024,1024]
    const float* wqkv = (const float*)d_in[1];  // [3072,1024]
    const float* emb  = (const float*)d_in[2];  // [32,16]
    const float* wout = (const float*)d_in[3];  // [1024,1024]
    float* out = (float*)d_out;                 // [8,1024,1024] fp32

    char* p = (char*)d_ws;
    bf16_t* hsb   = (bf16_t*)p; p += (size_t)8192 * 1024 * 2;  // 16 MB
    bf16_t* wqkvb = (bf16_t*)p; p += (size_t)3072 * 1024 * 2;  //  6 MB
    bf16_t* woutb = (bf16_t*)p; p += (size_t)1024 * 1024 * 2;  //  2 MB
    bf16_t* qlin  = (bf16_t*)p; p += (size_t)128 * 65536 * 2;  // 16 MB
    bf16_t* klin  = (bf16_t*)p; p += (size_t)128 * 65536 * 2;  // 16 MB
    bf16_t* vlin  = (bf16_t*)p; p += (size_t)128 * 65536 * 2;  // 16 MB
    bf16_t* attnb = (bf16_t*)p; p += (size_t)8192 * 1024 * 2;  // 16 MB
    float*  tab   = (float*)p;                                 // 128 KB

    f2b_kernel<<<2048, 256, 0, stream>>>(hs, hsb, 8192 * 1024 / 4);
    f2b_kernel<<<768, 256, 0, stream>>>(wqkv, wqkvb, 3072 * 1024 / 4);
    f2b_kernel<<<256, 256, 0, stream>>>(wout, woutb, 1024 * 1024 / 4);
    build_bias_tab<<<8, 256, 0, stream>>>(emb, tab);

    gemm_mfma<1, bf16_t><<<1536, 256, 0, stream>>>(hsb, wqkvb, (bf16_t*)nullptr, 3072, 24,
                                                   qlin, klin, vlin);
    attn_mfma4<<<1024, 256, 0, stream>>>(qlin, tab, klin, vlin, attnb);
    gemm_mfma<0, float><<<512, 256, 0, stream>>>(attnb, woutb, out, 1024, 8,
                                                 nullptr, nullptr, nullptr);
}